// Round 1
// baseline (446.141 us; speedup 1.0000x reference)
//
#include <hip/hip_runtime.h>
#include <hip/hip_bf16.h>
#include <math.h>

#define Bb 32
#define Cc 512
#define HW 3136        // 56*56
#define G  32
#define GS 16
#define Nn (Bb*HW)     // 100352
#define EPSF 1e-3f
#define TRI 136        // 16*17/2
#define STATS (TRI+GS) // 152: [0..15] sums, [16..151] upper-tri cross products

// upper-triangle pack (i<=j): idx = i*16 - i*(i+1)/2 + j, range 0..135
#define TIDX(i,j) ((i)*GS - (i)*((i)+1)/2 + (j))

// ---------------- Kernel 1: per-(b,g) partial sums + cross-products ----------------
__global__ __launch_bounds__(256) void stats_kernel(const float* __restrict__ x,
                                                    float* __restrict__ part) {
    const int blk = blockIdx.x;      // b*G + g
    const int b = blk / G;
    const int g = blk % G;
    const float* base = x + ((size_t)b * Cc + (size_t)g * GS) * HW;

    float s[GS];
    float c[TRI];
#pragma unroll
    for (int i = 0; i < GS; i++) s[i] = 0.f;
#pragma unroll
    for (int i = 0; i < TRI; i++) c[i] = 0.f;

    for (int p = threadIdx.x; p < HW; p += 256) {
        float v[GS];
#pragma unroll
        for (int j = 0; j < GS; j++) v[j] = base[(size_t)j * HW + p];
#pragma unroll
        for (int j = 0; j < GS; j++) s[j] += v[j];
#pragma unroll
        for (int i = 0; i < GS; i++) {
#pragma unroll
            for (int j = i; j < GS; j++) {
                c[TIDX(i, j)] += v[i] * v[j];
            }
        }
    }

    // wave-level butterfly reduce (64 lanes)
#pragma unroll
    for (int m = 1; m < 64; m <<= 1) {
#pragma unroll
        for (int i = 0; i < GS; i++) s[i] += __shfl_xor(s[i], m, 64);
#pragma unroll
        for (int i = 0; i < TRI; i++) c[i] += __shfl_xor(c[i], m, 64);
    }

    __shared__ float red[4][STATS];
    const int wave = threadIdx.x >> 6;
    const int lane = threadIdx.x & 63;
    if (lane == 0) {
#pragma unroll
        for (int i = 0; i < GS; i++) red[wave][i] = s[i];
#pragma unroll
        for (int i = 0; i < TRI; i++) red[wave][GS + i] = c[i];
    }
    __syncthreads();
    if (threadIdx.x < STATS) {
        float t = red[0][threadIdx.x] + red[1][threadIdx.x] +
                  red[2][threadIdx.x] + red[3][threadIdx.x];
        part[((size_t)g * Bb + b) * STATS + threadIdx.x] = t;
    }
}

// ---------------- Kernel 2: reduce partials, Cholesky, invert, pack L^-1 + bias ----------------
__global__ __launch_bounds__(64) void solve_kernel(const float* __restrict__ part,
                                                   float* __restrict__ wl) {
    const int g = blockIdx.x;
    const int t = threadIdx.x;

    __shared__ float st[STATS];
    __shared__ float cov[GS][GS];
    __shared__ float L[GS][GS];
    __shared__ float Li[GS][GS];
    __shared__ float m[GS];

    // reduce 32 per-batch partials
    for (int k = t; k < STATS; k += 64) {
        float acc = 0.f;
        for (int b = 0; b < Bb; b++)
            acc += part[((size_t)g * Bb + b) * STATS + k];
        st[k] = acc;
    }
    __syncthreads();

    if (t < GS) m[t] = st[t] * (1.0f / (float)Nn);
    __syncthreads();

    // shrunken covariance: (1-eps)*(E[xx]-mm) + eps*I
    for (int e = t; e < GS * GS; e += 64) {
        int i = e >> 4, j = e & 15;
        int ii = i < j ? i : j;
        int jj = i < j ? j : i;
        float cv = st[GS + TIDX(ii, jj)] * (1.0f / (float)Nn) - m[i] * m[j];
        cv *= (1.0f - EPSF);
        if (i == j) cv += EPSF;
        cov[i][j] = cv;
    }
    __syncthreads();

    // Cholesky (thread 0, sequential — 16x16 is tiny)
    if (t == 0) {
        for (int k = 0; k < GS; k++) {
            float d = cov[k][k];
            for (int r = 0; r < k; r++) d -= L[k][r] * L[k][r];
            d = sqrtf(d);
            L[k][k] = d;
            float inv = 1.0f / d;
            for (int i = k + 1; i < GS; i++) {
                float v = cov[i][k];
                for (int r = 0; r < k; r++) v -= L[i][r] * L[k][r];
                L[i][k] = v * inv;
            }
        }
    }
    __syncthreads();

    // forward substitution: column j of L^-1 (16 threads, one per column)
    if (t < GS) {
        const int j = t;
        for (int i = 0; i < GS; i++) Li[i][j] = 0.f;
        for (int i = j; i < GS; i++) {
            float v = (i == j) ? 1.f : 0.f;
            for (int k = j; k < i; k++) v -= L[i][k] * Li[k][j];
            Li[i][j] = v / L[i][i];
        }
    }
    __syncthreads();

    // pack: wl[g][0..135] = lower-tri L^-1 (idx i*(i+1)/2+j), wl[g][136..151] = bias = L^-1 m
    float* wg = wl + (size_t)g * STATS;
    for (int e = t; e < GS * GS; e += 64) {
        int i = e >> 4, j = e & 15;
        if (j <= i) wg[i * (i + 1) / 2 + j] = Li[i][j];
    }
    if (t < GS) {
        float bias = 0.f;
        for (int j = 0; j <= t; j++) bias += Li[t][j] * m[j];
        wg[TRI + t] = bias;
    }
}

// ---------------- Kernel 3: out = L^-1 x - bias ----------------
__global__ __launch_bounds__(256) void apply_kernel(const float* __restrict__ x,
                                                    const float* __restrict__ wl,
                                                    float* __restrict__ out) {
    const int blk = blockIdx.x;   // ((b*G+g)<<1) | s
    const int s = blk & 1;
    const int bg = blk >> 1;
    const int b = bg / G;
    const int g = bg % G;

    const float* __restrict__ wg = wl + (size_t)g * STATS;
    float Lt[TRI];
    float bias[GS];
#pragma unroll
    for (int i = 0; i < TRI; i++) Lt[i] = wg[i];
#pragma unroll
    for (int i = 0; i < GS; i++) bias[i] = wg[TRI + i];

    const size_t base_off = ((size_t)b * Cc + (size_t)g * GS) * HW + (size_t)s * (HW / 2);
    const float* __restrict__ xb = x + base_off;
    float* __restrict__ ob = out + base_off;

    for (int p = threadIdx.x; p < HW / 2; p += 256) {
        float v[GS];
#pragma unroll
        for (int j = 0; j < GS; j++) v[j] = xb[(size_t)j * HW + p];
#pragma unroll
        for (int i = 0; i < GS; i++) {
            float o = -bias[i];
#pragma unroll
            for (int j = 0; j <= i; j++) o += Lt[i * (i + 1) / 2 + j] * v[j];
            ob[(size_t)i * HW + p] = o;
        }
    }
}

extern "C" void kernel_launch(void* const* d_in, const int* in_sizes, int n_in,
                              void* d_out, int out_size, void* d_ws, size_t ws_size,
                              hipStream_t stream) {
    const float* x = (const float*)d_in[0];
    float* out = (float*)d_out;

    float* part = (float*)d_ws;                         // G*Bb*STATS floats
    float* wl = part + (size_t)G * Bb * STATS;          // G*STATS floats

    stats_kernel<<<Bb * G, 256, 0, stream>>>(x, part);
    solve_kernel<<<G, 64, 0, stream>>>(part, wl);
    apply_kernel<<<Bb * G * 2, 256, 0, stream>>>(x, wl, out);
}

// Round 3
// 431.210 us; speedup vs baseline: 1.0346x; 1.0346x over previous
//
#include <hip/hip_runtime.h>
#include <hip/hip_bf16.h>
#include <math.h>

#define Bb 32
#define Cc 512
#define HW 3136        // 56*56
#define HW4 784        // HW/4
#define G  32
#define GS 16
#define Nn (Bb*HW)     // 100352
#define EPSF 1e-3f
#define TRI 136        // 16*17/2
#define STATS (TRI+GS) // 152: [0..15] sums, [16..151] upper-tri cross products

typedef float floatx4 __attribute__((ext_vector_type(4)));

// upper-triangle pack (i<=j): idx = i*16 - i*(i+1)/2 + j, range 0..135
#define TIDX(i,j) ((i)*GS - (i)*((i)+1)/2 + (j))

// ---------------- Kernel 1: per-(b,g) partial sums + cross-products ----------------
__global__ __launch_bounds__(256) void stats_kernel(const float* __restrict__ x,
                                                    float* __restrict__ part) {
    const int blk = blockIdx.x;      // b*G + g
    const int b = blk / G;
    const int g = blk % G;
    const float* base = x + ((size_t)b * Cc + (size_t)g * GS) * HW;

    float s[GS];
    float c[TRI];
#pragma unroll
    for (int i = 0; i < GS; i++) s[i] = 0.f;
#pragma unroll
    for (int i = 0; i < TRI; i++) c[i] = 0.f;

    for (int p = threadIdx.x; p < HW; p += 256) {
        float v[GS];
#pragma unroll
        for (int j = 0; j < GS; j++) v[j] = base[(size_t)j * HW + p];
#pragma unroll
        for (int j = 0; j < GS; j++) s[j] += v[j];
#pragma unroll
        for (int i = 0; i < GS; i++) {
#pragma unroll
            for (int j = i; j < GS; j++) {
                c[TIDX(i, j)] += v[i] * v[j];
            }
        }
    }

    // wave-level butterfly reduce (64 lanes)
#pragma unroll
    for (int m = 1; m < 64; m <<= 1) {
#pragma unroll
        for (int i = 0; i < GS; i++) s[i] += __shfl_xor(s[i], m, 64);
#pragma unroll
        for (int i = 0; i < TRI; i++) c[i] += __shfl_xor(c[i], m, 64);
    }

    __shared__ float red[4][STATS];
    const int wave = threadIdx.x >> 6;
    const int lane = threadIdx.x & 63;
    if (lane == 0) {
#pragma unroll
        for (int i = 0; i < GS; i++) red[wave][i] = s[i];
#pragma unroll
        for (int i = 0; i < TRI; i++) red[wave][GS + i] = c[i];
    }
    __syncthreads();
    if (threadIdx.x < STATS) {
        float t = red[0][threadIdx.x] + red[1][threadIdx.x] +
                  red[2][threadIdx.x] + red[3][threadIdx.x];
        part[((size_t)g * Bb + b) * STATS + threadIdx.x] = t;
    }
}

// ---------------- Kernel 2: reduce partials, Cholesky, invert, pack L^-1 + bias ----------------
__global__ __launch_bounds__(64) void solve_kernel(const float* __restrict__ part,
                                                   float* __restrict__ wl) {
    const int g = blockIdx.x;
    const int t = threadIdx.x;

    __shared__ float st[STATS];
    __shared__ float cov[GS][GS];
    __shared__ float L[GS][GS];
    __shared__ float Li[GS][GS];
    __shared__ float m[GS];

    // reduce 32 per-batch partials
    for (int k = t; k < STATS; k += 64) {
        float acc = 0.f;
#pragma unroll
        for (int b = 0; b < Bb; b++)
            acc += part[((size_t)g * Bb + b) * STATS + k];
        st[k] = acc;
    }
    __syncthreads();

    if (t < GS) m[t] = st[t] * (1.0f / (float)Nn);
    __syncthreads();

    // shrunken covariance: (1-eps)*(E[xx]-mm) + eps*I
    for (int e = t; e < GS * GS; e += 64) {
        int i = e >> 4, j = e & 15;
        int ii = i < j ? i : j;
        int jj = i < j ? j : i;
        float cv = st[GS + TIDX(ii, jj)] * (1.0f / (float)Nn) - m[i] * m[j];
        cv *= (1.0f - EPSF);
        if (i == j) cv += EPSF;
        cov[i][j] = cv;
    }
    __syncthreads();

    // Cholesky (thread 0, sequential — 16x16 is tiny)
    if (t == 0) {
        for (int k = 0; k < GS; k++) {
            float d = cov[k][k];
            for (int r = 0; r < k; r++) d -= L[k][r] * L[k][r];
            d = sqrtf(d);
            L[k][k] = d;
            float inv = 1.0f / d;
            for (int i = k + 1; i < GS; i++) {
                float v = cov[i][k];
                for (int r = 0; r < k; r++) v -= L[i][r] * L[k][r];
                L[i][k] = v * inv;
            }
        }
    }
    __syncthreads();

    // forward substitution: column j of L^-1 (16 threads, one per column)
    if (t < GS) {
        const int j = t;
        for (int i = 0; i < GS; i++) Li[i][j] = 0.f;
        for (int i = j; i < GS; i++) {
            float v = (i == j) ? 1.f : 0.f;
            for (int k = j; k < i; k++) v -= L[i][k] * Li[k][j];
            Li[i][j] = v / L[i][i];
        }
    }
    __syncthreads();

    // pack: wl[g][0..135] = lower-tri L^-1 (idx i*(i+1)/2+j), wl[g][136..151] = bias = L^-1 m
    float* wg = wl + (size_t)g * STATS;
    for (int e = t; e < GS * GS; e += 64) {
        int i = e >> 4, j = e & 15;
        if (j <= i) wg[i * (i + 1) / 2 + j] = Li[i][j];
    }
    if (t < GS) {
        float bias = 0.f;
        for (int j = 0; j <= t; j++) bias += Li[t][j] * m[j];
        wg[TRI + t] = bias;
    }
}

// ---------------- Kernel 3: out = L^-1 x - bias (float4, NT stores) ----------------
__global__ __launch_bounds__(256) void apply_kernel(const float* __restrict__ x,
                                                    const float* __restrict__ wl,
                                                    float* __restrict__ out) {
    const int blk = blockIdx.x;   // b*G + g
    const int b = blk / G;
    const int g = blk % G;

    const float* __restrict__ wg = wl + (size_t)g * STATS;
    // block-uniform loads -> expect s_load promotion
    float Lt[TRI];
    float bias[GS];
#pragma unroll
    for (int i = 0; i < TRI; i++) Lt[i] = wg[i];
#pragma unroll
    for (int i = 0; i < GS; i++) bias[i] = wg[TRI + i];

    const size_t base_off = ((size_t)b * Cc + (size_t)g * GS) * HW;
    const floatx4* __restrict__ xb4 = reinterpret_cast<const floatx4*>(x + base_off);
    floatx4* __restrict__ ob4 = reinterpret_cast<floatx4*>(out + base_off);

    for (int p = threadIdx.x; p < HW4; p += 256) {
        floatx4 v[GS];
#pragma unroll
        for (int j = 0; j < GS; j++) v[j] = xb4[(size_t)j * HW4 + p];
#pragma unroll
        for (int i = 0; i < GS; i++) {
            floatx4 o = (floatx4)(-bias[i]);
#pragma unroll
            for (int j = 0; j <= i; j++) {
                o += Lt[i * (i + 1) / 2 + j] * v[j];
            }
            __builtin_nontemporal_store(o, &ob4[(size_t)i * HW4 + p]);
        }
    }
}

extern "C" void kernel_launch(void* const* d_in, const int* in_sizes, int n_in,
                              void* d_out, int out_size, void* d_ws, size_t ws_size,
                              hipStream_t stream) {
    const float* x = (const float*)d_in[0];
    float* out = (float*)d_out;

    float* part = (float*)d_ws;                         // G*Bb*STATS floats
    float* wl = part + (size_t)G * Bb * STATS;          // G*STATS floats

    stats_kernel<<<Bb * G, 256, 0, stream>>>(x, part);
    solve_kernel<<<G, 64, 0, stream>>>(part, wl);
    apply_kernel<<<Bb * G, 256, 0, stream>>>(x, wl, out);
}